// Round 1
// baseline (224.437 us; speedup 1.0000x reference)
//
#include <hip/hip_runtime.h>
#include <math.h>

#define B_   4
#define L_   4096
#define H_   16
#define NB_  32
#define C_   512        // H_*NB_
#define DM_  1024
#define HID_ 128
#define M_   (B_*L_)    // 16384
#define NC_  64         // number of L-chunks for the scan
#define CT_  64         // chunk length; NC_*CT_ == L_

// ---------------- GEMM1: Hb[M,128] = gelu(X[M,1024] @ W1[1024,128] + b1) ----------------
__global__ __launch_bounds__(256) void k_gemm1(const float* __restrict__ X,
                                               const float* __restrict__ W1,
                                               const float* __restrict__ b1,
                                               float* __restrict__ Hb) {
  __shared__ float As[16][68];    // [BK][BM+pad], A stored transposed
  __shared__ float Bs[16][132];   // [BK][BN+pad]
  const int tid = threadIdx.x;
  const int m0  = blockIdx.x * 64;
  const int tr  = tid >> 4;       // 0..15 (row group of 4)
  const int tc  = tid & 15;       // 0..15 (col group of 8)
  float acc[4][8];
#pragma unroll
  for (int i = 0; i < 4; ++i)
#pragma unroll
    for (int j = 0; j < 8; ++j) acc[i][j] = 0.f;

  for (int k0 = 0; k0 < DM_; k0 += 16) {
    {   // A tile: 64 rows x 16 k, one float4 per thread, store transposed
      int r  = tid >> 2;            // 0..63
      int c4 = (tid & 3) << 2;      // 0,4,8,12
      float4 v = *(const float4*)(X + (size_t)(m0 + r) * DM_ + k0 + c4);
      As[c4 + 0][r] = v.x; As[c4 + 1][r] = v.y;
      As[c4 + 2][r] = v.z; As[c4 + 3][r] = v.w;
    }
    {   // B tile: 16 rows x 128 cols, two float4 per thread
      int r  = tid >> 5;            // 0..7
      int c4 = (tid & 31) << 2;     // 0..124
      *(float4*)&Bs[r][c4]     = *(const float4*)(W1 + (size_t)(k0 + r) * HID_ + c4);
      *(float4*)&Bs[r + 8][c4] = *(const float4*)(W1 + (size_t)(k0 + r + 8) * HID_ + c4);
    }
    __syncthreads();
#pragma unroll
    for (int kk = 0; kk < 16; ++kk) {
      float4 av = *(const float4*)&As[kk][tr << 2];
      float4 bu = *(const float4*)&Bs[kk][tc << 3];
      float4 bv = *(const float4*)&Bs[kk][(tc << 3) + 4];
      float a[4]  = {av.x, av.y, av.z, av.w};
      float bb[8] = {bu.x, bu.y, bu.z, bu.w, bv.x, bv.y, bv.z, bv.w};
#pragma unroll
      for (int i = 0; i < 4; ++i)
#pragma unroll
        for (int j = 0; j < 8; ++j) acc[i][j] += a[i] * bb[j];
    }
    __syncthreads();
  }
  // epilogue: exact gelu
#pragma unroll
  for (int i = 0; i < 4; ++i) {
    int m = m0 + (tr << 2) + i;
#pragma unroll
    for (int j = 0; j < 8; ++j) {
      int c = (tc << 3) + j;
      float x = acc[i][j] + b1[c];
      float g = 0.5f * x * (1.0f + erff(x * 0.70710678f));
      Hb[(size_t)m * HID_ + c] = g;
    }
  }
}

// ------ GEMM2: logR = clip(Hb @ W2 + b2, +-5); writes Pi (out1), K (out2), R (out3) ------
__global__ __launch_bounds__(256) void k_gemm2(const float* __restrict__ Hb,
                                               const float* __restrict__ W2,
                                               const float* __restrict__ b2,
                                               const float* __restrict__ logPi,
                                               float* __restrict__ out1,
                                               float* __restrict__ out2,
                                               float* __restrict__ out3) {
  __shared__ float As[16][68];
  __shared__ float Bs[16][132];
  const int tid = threadIdx.x;
  const int m0  = blockIdx.x * 64;
  const int n0  = blockIdx.y * 128;
  const int tr  = tid >> 4;
  const int tc  = tid & 15;
  float acc[4][8];
#pragma unroll
  for (int i = 0; i < 4; ++i)
#pragma unroll
    for (int j = 0; j < 8; ++j) acc[i][j] = 0.f;

  for (int k0 = 0; k0 < HID_; k0 += 16) {
    {
      int r  = tid >> 2;
      int c4 = (tid & 3) << 2;
      float4 v = *(const float4*)(Hb + (size_t)(m0 + r) * HID_ + k0 + c4);
      As[c4 + 0][r] = v.x; As[c4 + 1][r] = v.y;
      As[c4 + 2][r] = v.z; As[c4 + 3][r] = v.w;
    }
    {
      int r  = tid >> 5;
      int c4 = (tid & 31) << 2;
      *(float4*)&Bs[r][c4]     = *(const float4*)(W2 + (size_t)(k0 + r) * C_ + n0 + c4);
      *(float4*)&Bs[r + 8][c4] = *(const float4*)(W2 + (size_t)(k0 + r + 8) * C_ + n0 + c4);
    }
    __syncthreads();
#pragma unroll
    for (int kk = 0; kk < 16; ++kk) {
      float4 av = *(const float4*)&As[kk][tr << 2];
      float4 bu = *(const float4*)&Bs[kk][tc << 3];
      float4 bv = *(const float4*)&Bs[kk][(tc << 3) + 4];
      float a[4]  = {av.x, av.y, av.z, av.w};
      float bb[8] = {bu.x, bu.y, bu.z, bu.w, bv.x, bv.y, bv.z, bv.w};
#pragma unroll
      for (int i = 0; i < 4; ++i)
#pragma unroll
        for (int j = 0; j < 8; ++j) acc[i][j] += a[i] * bb[j];
    }
    __syncthreads();
  }
  // epilogue
#pragma unroll
  for (int i = 0; i < 4; ++i) {
    int m = m0 + (tr << 2) + i;
    size_t rowbase = (size_t)m * C_;
#pragma unroll
    for (int jj = 0; jj < 8; jj += 4) {
      int c = n0 + (tc << 3) + jj;
      float4 r4, k4, p4;
      float* r4p = &r4.x; float* k4p = &k4.x; float* p4p = &p4.x;
#pragma unroll
      for (int q = 0; q < 4; ++q) {
        float lr = acc[i][jj + q] + b2[c + q];
        lr = fminf(5.0f, fmaxf(-5.0f, lr));
        float R  = expf(lr);
        float Pi = expf(logPi[c + q]);
        float Kv = Pi / fmaxf(Pi + R, 1e-8f);
        r4p[q] = R; p4p[q] = Pi; k4p[q] = Kv;
      }
      *(float4*)&out3[rowbase + c] = r4;
      *(float4*)&out2[rowbase + c] = k4;
      *(float4*)&out1[rowbase + c] = p4;
    }
  }
}

// --------------- scan phase 1: per-chunk affine composition (A,U) ---------------
__global__ __launch_bounds__(512) void k_scan1(const float* __restrict__ Kv,
                                               const float* __restrict__ theta,
                                               float* __restrict__ Ab,
                                               float* __restrict__ Ub) {
  const int b  = blockIdx.x / NC_;
  const int ch = blockIdx.x % NC_;
  const int c  = threadIdx.x;
  size_t base = ((size_t)b * L_ + (size_t)ch * CT_) * C_ + c;
  float A = 1.f, U = 0.f;
  for (int j = 0; j < CT_; ++j) {
    size_t idx = base + (size_t)j * C_;
    float k  = Kv[idx];
    float th = theta[idx];
    float nu = atan2f(sinf(-th), cosf(-th));
    float a = 1.f - k;
    U = a * U + k * nu;
    A = a * A;
  }
  size_t o = ((size_t)b * NC_ + ch) * C_ + c;
  Ab[o] = A; Ub[o] = U;
}

// --------------- scan phase 2: prefix over chunks -> carry-in d per chunk ---------------
__global__ __launch_bounds__(64) void k_scan2(const float* __restrict__ Ab,
                                              const float* __restrict__ Ub,
                                              float* __restrict__ D0) {
  const int b = blockIdx.x / (C_ / 64);
  const int g = blockIdx.x % (C_ / 64);
  const int c = g * 64 + threadIdx.x;
  float Up = 0.f;
  for (int i = 0; i < NC_; ++i) {
    size_t o = ((size_t)b * NC_ + i) * C_ + c;
    D0[o] = Up;                    // d before chunk i (d_{-1} = 0)
    float a = Ab[o], u = Ub[o];
    Up = a * Up + u;
  }
}

// --------------- scan phase 3: apply carry, write out0 = theta + d ---------------
__global__ __launch_bounds__(512) void k_scan3(const float* __restrict__ Kv,
                                               const float* __restrict__ theta,
                                               const float* __restrict__ D0,
                                               float* __restrict__ out0) {
  const int b  = blockIdx.x / NC_;
  const int ch = blockIdx.x % NC_;
  const int c  = threadIdx.x;
  size_t base = ((size_t)b * L_ + (size_t)ch * CT_) * C_ + c;
  float d = D0[((size_t)b * NC_ + ch) * C_ + c];
  for (int j = 0; j < CT_; ++j) {
    size_t idx = base + (size_t)j * C_;
    float k  = Kv[idx];
    float th = theta[idx];
    float nu = atan2f(sinf(-th), cosf(-th));
    d = (1.f - k) * d + k * nu;
    out0[idx] = th + d;
  }
}

extern "C" void kernel_launch(void* const* d_in, const int* in_sizes, int n_in,
                              void* d_out, int out_size, void* d_ws, size_t ws_size,
                              hipStream_t stream) {
  const float* theta = (const float*)d_in[0];
  const float* X     = (const float*)d_in[1];
  const float* logPi = (const float*)d_in[2];
  const float* W1    = (const float*)d_in[3];
  const float* b1    = (const float*)d_in[4];
  const float* W2    = (const float*)d_in[5];
  const float* b2    = (const float*)d_in[6];

  float* out = (float*)d_out;
  const size_t S = (size_t)M_ * C_;      // 8388608 per output tensor
  float* out0 = out;
  float* out1 = out + S;
  float* out2 = out + 2 * S;
  float* out3 = out + 3 * S;

  float* Hb = (float*)d_ws;                            // M*HID floats (8 MiB)
  float* Ab = Hb + (size_t)M_ * HID_;                  // B*NC*C
  float* Ub = Ab + (size_t)B_ * NC_ * C_;
  float* D0 = Ub + (size_t)B_ * NC_ * C_;

  hipLaunchKernelGGL(k_gemm1, dim3(M_ / 64), dim3(256), 0, stream, X, W1, b1, Hb);
  hipLaunchKernelGGL(k_gemm2, dim3(M_ / 64, C_ / 128), dim3(256), 0, stream,
                     Hb, W2, b2, logPi, out1, out2, out3);
  hipLaunchKernelGGL(k_scan1, dim3(B_ * NC_), dim3(C_), 0, stream, out2, theta, Ab, Ub);
  hipLaunchKernelGGL(k_scan2, dim3(B_ * (C_ / 64)), dim3(64), 0, stream, Ab, Ub, D0);
  hipLaunchKernelGGL(k_scan3, dim3(B_ * NC_), dim3(C_), 0, stream, out2, theta, D0, out0);
}

// Round 2
// 85.893 us; speedup vs baseline: 2.6130x; 2.6130x over previous
//
#include <hip/hip_runtime.h>
#include <math.h>

#define B_   4
#define L_   4096
#define H_   16
#define NB_  32
#define C_   512
#define DM_  1024
#define HID_ 128
#define M_   (B_*L_)    // 16384
#define NC_  128        // L-chunks for scan
#define CT_  32         // chunk length

typedef __attribute__((ext_vector_type(8))) short short8;
typedef __attribute__((ext_vector_type(4))) float f32x4;

__device__ __forceinline__ unsigned short f2bf(float f) {
  unsigned u = __float_as_uint(f);
  u += 0x7fffu + ((u >> 16) & 1u);      // round-to-nearest-even
  return (unsigned short)(u >> 16);
}

// wrap(-theta) into (-pi, pi] == atan2(sin(-t), cos(-t)) up to ~1e-7
__device__ __forceinline__ float wrap_neg(float th) {
  return 6.283185307179586f * rintf(th * 0.15915494309189535f) - th;
}

// ---- prep: W1T[n][k] = bf16(W1[k][n]) (1024x128 -> 128x1024); W2T likewise (128x512 -> 512x128)
__global__ __launch_bounds__(256) void k_prep(const float* __restrict__ W1,
                                              const float* __restrict__ W2,
                                              unsigned short* __restrict__ W1T,
                                              unsigned short* __restrict__ W2T) {
  int idx = blockIdx.x * 256 + threadIdx.x;
  if (idx < DM_ * HID_) {                       // 131072
    int n = idx >> 10, k = idx & 1023;
    W1T[idx] = f2bf(W1[(size_t)k * HID_ + n]);
  }
  int i2 = idx - DM_ * HID_;
  if (i2 >= 0 && i2 < HID_ * C_) {              // 65536
    int n = i2 >> 7, k = i2 & 127;
    W2T[i2] = f2bf(W2[(size_t)k * C_ + n]);
  }
}

// ---- GEMM1 (MFMA): Hb[M,128] = bf16(gelu(X @ W1 + b1)); BM=64, BN=128, BK=64, 512 thr
__global__ __launch_bounds__(512) void k_gemm1(const float* __restrict__ X,
                                               const unsigned short* __restrict__ W1T,
                                               const float* __restrict__ b1,
                                               unsigned short* __restrict__ Hb) {
  __shared__ char lds[24576];                   // A 64x64 bf16 @0, B 128x64 bf16 @8192
  const int tid  = threadIdx.x;
  const int m0   = blockIdx.x * 64;
  const int lane = tid & 63;
  const int wave = tid >> 6;                    // 0..7
  const int wr   = wave >> 2;                   // 0..1
  const int wc   = wave & 3;                    // 0..3
  const int fr   = lane & 15;
  const int kg   = lane >> 4;

  f32x4 acc[2][2];
#pragma unroll
  for (int i = 0; i < 2; ++i)
#pragma unroll
    for (int j = 0; j < 2; ++j) acc[i][j] = (f32x4){0.f, 0.f, 0.f, 0.f};

  for (int k0 = 0; k0 < DM_; k0 += 64) {
    {   // A: 512 chunks of 8 f32 -> bf16, XOR-swizzled
      int row = tid >> 3, k8 = tid & 7;
      const float4* src = (const float4*)(X + (size_t)(m0 + row) * DM_ + k0 + k8 * 8);
      float4 v0 = src[0], v1 = src[1];
      uint4 pk;
      pk.x = f2bf(v0.x) | ((unsigned)f2bf(v0.y) << 16);
      pk.y = f2bf(v0.z) | ((unsigned)f2bf(v0.w) << 16);
      pk.z = f2bf(v1.x) | ((unsigned)f2bf(v1.y) << 16);
      pk.w = f2bf(v1.z) | ((unsigned)f2bf(v1.w) << 16);
      *(uint4*)(lds + row * 128 + ((k8 ^ (row & 7)) << 4)) = pk;
    }
#pragma unroll
    for (int t = 0; t < 2; ++t) {   // B: 1024 chunks of 16B bf16
      int c = tid + t * 512;
      int n = c >> 3, k8 = c & 7;
      uint4 v = *(const uint4*)(W1T + (size_t)n * DM_ + k0 + k8 * 8);
      *(uint4*)(lds + 8192 + n * 128 + ((k8 ^ (n & 7)) << 4)) = v;
    }
    __syncthreads();
#pragma unroll
    for (int ks = 0; ks < 2; ++ks) {
      short8 a[2], b[2];
#pragma unroll
      for (int i = 0; i < 2; ++i) {
        int row = wr * 32 + i * 16 + fr;
        a[i] = *(const short8*)(lds + row * 128 + (((ks * 4 + kg) ^ (row & 7)) << 4));
      }
#pragma unroll
      for (int j = 0; j < 2; ++j) {
        int col = wc * 32 + j * 16 + fr;
        b[j] = *(const short8*)(lds + 8192 + col * 128 + (((ks * 4 + kg) ^ (col & 7)) << 4));
      }
#pragma unroll
      for (int i = 0; i < 2; ++i)
#pragma unroll
        for (int j = 0; j < 2; ++j)
          acc[i][j] = __builtin_amdgcn_mfma_f32_16x16x32_bf16(a[i], b[j], acc[i][j], 0, 0, 0);
    }
    __syncthreads();
  }
#pragma unroll
  for (int i = 0; i < 2; ++i)
#pragma unroll
    for (int j = 0; j < 2; ++j) {
      int col = wc * 32 + j * 16 + fr;
      float bb = b1[col];
#pragma unroll
      for (int r = 0; r < 4; ++r) {
        int row = m0 + wr * 32 + i * 16 + kg * 4 + r;
        float x = acc[i][j][r] + bb;
        float g = 0.5f * x * (1.0f + erff(x * 0.70710678f));
        Hb[(size_t)row * HID_ + col] = f2bf(g);
      }
    }
}

// ---- GEMM2 (MFMA) + epilogue: logR=clip(Hb@W2+b2); write Pi,K,R; BM=64,BN=128,BK=64
__global__ __launch_bounds__(512) void k_gemm2(const unsigned short* __restrict__ Hb,
                                               const unsigned short* __restrict__ W2T,
                                               const float* __restrict__ b2,
                                               const float* __restrict__ logPi,
                                               float* __restrict__ out1,
                                               float* __restrict__ out2,
                                               float* __restrict__ out3) {
  __shared__ char lds[24576];
  const int tid  = threadIdx.x;
  const int m0   = blockIdx.x * 64;
  const int n0   = blockIdx.y * 128;
  const int lane = tid & 63;
  const int wave = tid >> 6;
  const int wr   = wave >> 2;
  const int wc   = wave & 3;
  const int fr   = lane & 15;
  const int kg   = lane >> 4;

  f32x4 acc[2][2];
#pragma unroll
  for (int i = 0; i < 2; ++i)
#pragma unroll
    for (int j = 0; j < 2; ++j) acc[i][j] = (f32x4){0.f, 0.f, 0.f, 0.f};

  for (int k0 = 0; k0 < HID_; k0 += 64) {
    {   // A: Hb already bf16
      int row = tid >> 3, k8 = tid & 7;
      uint4 v = *(const uint4*)(Hb + (size_t)(m0 + row) * HID_ + k0 + k8 * 8);
      *(uint4*)(lds + row * 128 + ((k8 ^ (row & 7)) << 4)) = v;
    }
#pragma unroll
    for (int t = 0; t < 2; ++t) {
      int c = tid + t * 512;
      int n = c >> 3, k8 = c & 7;
      uint4 v = *(const uint4*)(W2T + (size_t)(n0 + n) * HID_ + k0 + k8 * 8);
      *(uint4*)(lds + 8192 + n * 128 + ((k8 ^ (n & 7)) << 4)) = v;
    }
    __syncthreads();
#pragma unroll
    for (int ks = 0; ks < 2; ++ks) {
      short8 a[2], b[2];
#pragma unroll
      for (int i = 0; i < 2; ++i) {
        int row = wr * 32 + i * 16 + fr;
        a[i] = *(const short8*)(lds + row * 128 + (((ks * 4 + kg) ^ (row & 7)) << 4));
      }
#pragma unroll
      for (int j = 0; j < 2; ++j) {
        int col = wc * 32 + j * 16 + fr;
        b[j] = *(const short8*)(lds + 8192 + col * 128 + (((ks * 4 + kg) ^ (col & 7)) << 4));
      }
#pragma unroll
      for (int i = 0; i < 2; ++i)
#pragma unroll
        for (int j = 0; j < 2; ++j)
          acc[i][j] = __builtin_amdgcn_mfma_f32_16x16x32_bf16(a[i], b[j], acc[i][j], 0, 0, 0);
    }
    __syncthreads();
  }
#pragma unroll
  for (int i = 0; i < 2; ++i)
#pragma unroll
    for (int j = 0; j < 2; ++j) {
      int col = n0 + wc * 32 + j * 16 + fr;
      float Pi = expf(logPi[col]);
      float bb = b2[col];
#pragma unroll
      for (int r = 0; r < 4; ++r) {
        int row = m0 + wr * 32 + i * 16 + kg * 4 + r;
        float lr = acc[i][j][r] + bb;
        lr = fminf(5.0f, fmaxf(-5.0f, lr));
        float R = expf(lr);
        float K = Pi / fmaxf(Pi + R, 1e-8f);
        size_t o = (size_t)row * C_ + col;
        out1[o] = Pi; out2[o] = K; out3[o] = R;
      }
    }
}

// ---- scan phase 1: per-chunk affine composition
__global__ __launch_bounds__(256) void k_scan1(const float* __restrict__ Kv,
                                               const float* __restrict__ theta,
                                               float* __restrict__ Ab,
                                               float* __restrict__ Ub) {
  const int b  = blockIdx.x / NC_;
  const int ch = blockIdx.x % NC_;
  const int c  = blockIdx.y * 256 + threadIdx.x;
  size_t base = ((size_t)b * L_ + (size_t)ch * CT_) * C_ + c;
  float A = 1.f, U = 0.f;
  for (int j = 0; j < CT_; ++j) {
    size_t idx = base + (size_t)j * C_;
    float k  = Kv[idx];
    float nu = wrap_neg(theta[idx]);
    float a  = 1.f - k;
    U = a * U + k * nu;
    A *= a;
  }
  size_t o = ((size_t)b * NC_ + ch) * C_ + c;
  Ab[o] = A; Ub[o] = U;
}

// ---- scan phase 2: serial prefix over chunks -> carry-in d per chunk
__global__ __launch_bounds__(256) void k_scan2(const float* __restrict__ Ab,
                                               const float* __restrict__ Ub,
                                               float* __restrict__ D0) {
  const int id = blockIdx.x * 256 + threadIdx.x;   // 0 .. B_*C_-1
  const int b = id / C_;
  const int c = id % C_;
  float Up = 0.f;
  for (int i = 0; i < NC_; ++i) {
    size_t o = ((size_t)b * NC_ + i) * C_ + c;
    D0[o] = Up;
    Up = Ab[o] * Up + Ub[o];
  }
}

// ---- scan phase 3: apply carry, out0 = theta + d
__global__ __launch_bounds__(256) void k_scan3(const float* __restrict__ Kv,
                                               const float* __restrict__ theta,
                                               const float* __restrict__ D0,
                                               float* __restrict__ out0) {
  const int b  = blockIdx.x / NC_;
  const int ch = blockIdx.x % NC_;
  const int c  = blockIdx.y * 256 + threadIdx.x;
  size_t base = ((size_t)b * L_ + (size_t)ch * CT_) * C_ + c;
  float d = D0[((size_t)b * NC_ + ch) * C_ + c];
  for (int j = 0; j < CT_; ++j) {
    size_t idx = base + (size_t)j * C_;
    float k  = Kv[idx];
    float th = theta[idx];
    float nu = wrap_neg(th);
    d = (1.f - k) * d + k * nu;
    out0[idx] = th + d;
  }
}

extern "C" void kernel_launch(void* const* d_in, const int* in_sizes, int n_in,
                              void* d_out, int out_size, void* d_ws, size_t ws_size,
                              hipStream_t stream) {
  const float* theta = (const float*)d_in[0];
  const float* X     = (const float*)d_in[1];
  const float* logPi = (const float*)d_in[2];
  const float* W1    = (const float*)d_in[3];
  const float* b1    = (const float*)d_in[4];
  const float* W2    = (const float*)d_in[5];
  const float* b2    = (const float*)d_in[6];

  float* out = (float*)d_out;
  const size_t S = (size_t)M_ * C_;
  float* out0 = out;
  float* out1 = out + S;
  float* out2 = out + 2 * S;
  float* out3 = out + 3 * S;

  unsigned short* Hb  = (unsigned short*)d_ws;           // M*HID bf16 (4 MiB)
  unsigned short* W1T = Hb + (size_t)M_ * HID_;          // 131072
  unsigned short* W2T = W1T + (size_t)DM_ * HID_;        // 65536
  float* Ab = (float*)(W2T + (size_t)HID_ * C_);         // B*NC*C each (1 MiB)
  float* Ub = Ab + (size_t)B_ * NC_ * C_;
  float* D0 = Ub + (size_t)B_ * NC_ * C_;

  hipLaunchKernelGGL(k_prep, dim3(768), dim3(256), 0, stream, W1, W2, W1T, W2T);
  hipLaunchKernelGGL(k_gemm1, dim3(M_ / 64), dim3(512), 0, stream, X, W1T, b1, Hb);
  hipLaunchKernelGGL(k_gemm2, dim3(M_ / 64, C_ / 128), dim3(512), 0, stream,
                     Hb, W2T, b2, logPi, out1, out2, out3);
  hipLaunchKernelGGL(k_scan1, dim3(B_ * NC_, 2), dim3(256), 0, stream, out2, theta, Ab, Ub);
  hipLaunchKernelGGL(k_scan2, dim3(B_ * C_ / 256), dim3(256), 0, stream, Ab, Ub, D0);
  hipLaunchKernelGGL(k_scan3, dim3(B_ * NC_, 2), dim3(256), 0, stream, out2, theta, D0, out0);
}

// Round 4
// 85.611 us; speedup vs baseline: 2.6216x; 1.0033x over previous
//
#include <hip/hip_runtime.h>
#include <math.h>

#define B_   4
#define L_   4096
#define C_   512
#define DM_  1024
#define HID_ 128
#define M_   (B_*L_)    // 16384
#define NC_  128        // chunks of 32 for scan2/scan3
#define CT_  32

typedef __attribute__((ext_vector_type(8))) short short8;
typedef __attribute__((ext_vector_type(4))) float f32x4;

__device__ __forceinline__ unsigned short f2bf(float f) {
  unsigned u = __float_as_uint(f);
  u += 0x7fffu + ((u >> 16) & 1u);
  return (unsigned short)(u >> 16);
}

// wrap(-theta) into (-pi, pi] == atan2(sin(-t), cos(-t))
__device__ __forceinline__ float wrap_neg(float th) {
  return 6.283185307179586f * rintf(th * 0.15915494309189535f) - th;
}

// ---- prep: transpose+cast weights to bf16 [n][k]
__global__ __launch_bounds__(256) void k_prep(const float* __restrict__ W1,
                                              const float* __restrict__ W2,
                                              unsigned short* __restrict__ W1T,
                                              unsigned short* __restrict__ W2T) {
  int idx = blockIdx.x * 256 + threadIdx.x;
  if (idx < DM_ * HID_) {
    int n = idx >> 10, k = idx & 1023;
    W1T[idx] = f2bf(W1[(size_t)k * HID_ + n]);
  }
  int i2 = idx - DM_ * HID_;
  if (i2 >= 0 && i2 < HID_ * C_) {
    int n = i2 >> 7, k = i2 & 127;
    W2T[i2] = f2bf(W2[(size_t)k * C_ + n]);
  }
}

// ---- GEMM1 (MFMA): Hb[M,128] = bf16(gelu(X @ W1 + b1))
__global__ __launch_bounds__(512) void k_gemm1(const float* __restrict__ X,
                                               const unsigned short* __restrict__ W1T,
                                               const float* __restrict__ b1,
                                               unsigned short* __restrict__ Hb) {
  __shared__ char lds[24576];
  const int tid  = threadIdx.x;
  const int m0   = blockIdx.x * 64;
  const int lane = tid & 63;
  const int wave = tid >> 6;
  const int wr   = wave >> 2;
  const int wc   = wave & 3;
  const int fr   = lane & 15;
  const int kg   = lane >> 4;

  f32x4 acc[2][2];
#pragma unroll
  for (int i = 0; i < 2; ++i)
#pragma unroll
    for (int j = 0; j < 2; ++j) acc[i][j] = (f32x4){0.f, 0.f, 0.f, 0.f};

  for (int k0 = 0; k0 < DM_; k0 += 64) {
    {
      int row = tid >> 3, k8 = tid & 7;
      const f32x4* src = (const f32x4*)(X + (size_t)(m0 + row) * DM_ + k0 + k8 * 8);
      f32x4 v0 = __builtin_nontemporal_load(src);
      f32x4 v1 = __builtin_nontemporal_load(src + 1);
      uint4 pk;
      pk.x = f2bf(v0[0]) | ((unsigned)f2bf(v0[1]) << 16);
      pk.y = f2bf(v0[2]) | ((unsigned)f2bf(v0[3]) << 16);
      pk.z = f2bf(v1[0]) | ((unsigned)f2bf(v1[1]) << 16);
      pk.w = f2bf(v1[2]) | ((unsigned)f2bf(v1[3]) << 16);
      *(uint4*)(lds + row * 128 + ((k8 ^ (row & 7)) << 4)) = pk;
    }
#pragma unroll
    for (int t = 0; t < 2; ++t) {
      int c = tid + t * 512;
      int n = c >> 3, k8 = c & 7;
      uint4 v = *(const uint4*)(W1T + (size_t)n * DM_ + k0 + k8 * 8);
      *(uint4*)(lds + 8192 + n * 128 + ((k8 ^ (n & 7)) << 4)) = v;
    }
    __syncthreads();
#pragma unroll
    for (int ks = 0; ks < 2; ++ks) {
      short8 a[2], b[2];
#pragma unroll
      for (int i = 0; i < 2; ++i) {
        int row = wr * 32 + i * 16 + fr;
        a[i] = *(const short8*)(lds + row * 128 + (((ks * 4 + kg) ^ (row & 7)) << 4));
      }
#pragma unroll
      for (int j = 0; j < 2; ++j) {
        int col = wc * 32 + j * 16 + fr;
        b[j] = *(const short8*)(lds + 8192 + col * 128 + (((ks * 4 + kg) ^ (col & 7)) << 4));
      }
#pragma unroll
      for (int i = 0; i < 2; ++i)
#pragma unroll
        for (int j = 0; j < 2; ++j)
          acc[i][j] = __builtin_amdgcn_mfma_f32_16x16x32_bf16(a[i], b[j], acc[i][j], 0, 0, 0);
    }
    __syncthreads();
  }
#pragma unroll
  for (int i = 0; i < 2; ++i)
#pragma unroll
    for (int j = 0; j < 2; ++j) {
      int col = wc * 32 + j * 16 + fr;
      float bb = b1[col];
#pragma unroll
      for (int r = 0; r < 4; ++r) {
        int row = m0 + wr * 32 + i * 16 + kg * 4 + r;
        float x = acc[i][j][r] + bb;
        float g = 0.5f * x * (1.0f + erff(x * 0.70710678f));
        Hb[(size_t)row * HID_ + col] = f2bf(g);
      }
    }
}

// ---- GEMM2 (MFMA) + epilogue (Pi,K,R) + fused scan phase-1 (per-32-row affine composites)
__global__ __launch_bounds__(512) void k_gemm2(const unsigned short* __restrict__ Hb,
                                               const unsigned short* __restrict__ W2T,
                                               const float* __restrict__ b2,
                                               const float* __restrict__ logPi,
                                               const float* __restrict__ theta,
                                               float* __restrict__ out1,
                                               float* __restrict__ out2,
                                               float* __restrict__ out3,
                                               float* __restrict__ Ab,
                                               float* __restrict__ Ub) {
  __shared__ char lds[71808];     // gemm phase uses [0,24576); scan phase uses full
  float* sA  = (float*)lds;               // [64][132]
  float* sU  = sA + 64 * 132;             // [64][132]
  float* sGA = sU + 64 * 132;             // [4][132] segment composites
  float* sGU = sGA + 4 * 132;             // [4][132]
  const int tid  = threadIdx.x;
  const int m0   = blockIdx.x * 64;
  const int n0   = blockIdx.y * 128;
  const int lane = tid & 63;
  const int wave = tid >> 6;
  const int wr   = wave >> 2;
  const int wc   = wave & 3;
  const int fr   = lane & 15;
  const int kg   = lane >> 4;

  f32x4 acc[2][2];
#pragma unroll
  for (int i = 0; i < 2; ++i)
#pragma unroll
    for (int j = 0; j < 2; ++j) acc[i][j] = (f32x4){0.f, 0.f, 0.f, 0.f};

  for (int k0 = 0; k0 < HID_; k0 += 64) {
    {
      int row = tid >> 3, k8 = tid & 7;
      uint4 v = *(const uint4*)(Hb + (size_t)(m0 + row) * HID_ + k0 + k8 * 8);
      *(uint4*)(lds + row * 128 + ((k8 ^ (row & 7)) << 4)) = v;
    }
#pragma unroll
    for (int t = 0; t < 2; ++t) {
      int c = tid + t * 512;
      int n = c >> 3, k8 = c & 7;
      uint4 v = *(const uint4*)(W2T + (size_t)(n0 + n) * HID_ + k0 + k8 * 8);
      *(uint4*)(lds + 8192 + n * 128 + ((k8 ^ (n & 7)) << 4)) = v;
    }
    __syncthreads();
#pragma unroll
    for (int ks = 0; ks < 2; ++ks) {
      short8 a[2], b[2];
#pragma unroll
      for (int i = 0; i < 2; ++i) {
        int row = wr * 32 + i * 16 + fr;
        a[i] = *(const short8*)(lds + row * 128 + (((ks * 4 + kg) ^ (row & 7)) << 4));
      }
#pragma unroll
      for (int j = 0; j < 2; ++j) {
        int col = wc * 32 + j * 16 + fr;
        b[j] = *(const short8*)(lds + 8192 + col * 128 + (((ks * 4 + kg) ^ (col & 7)) << 4));
      }
#pragma unroll
      for (int i = 0; i < 2; ++i)
#pragma unroll
        for (int j = 0; j < 2; ++j)
          acc[i][j] = __builtin_amdgcn_mfma_f32_16x16x32_bf16(a[i], b[j], acc[i][j], 0, 0, 0);
    }
    __syncthreads();
  }

  // epilogue: Pi/K/R writes + stash (a,u) in LDS
#pragma unroll
  for (int i = 0; i < 2; ++i)
#pragma unroll
    for (int j = 0; j < 2; ++j) {
      int col_l = wc * 32 + j * 16 + fr;
      int col = n0 + col_l;
      float Pi = expf(logPi[col]);
      float bb = b2[col];
#pragma unroll
      for (int r = 0; r < 4; ++r) {
        int row_l = wr * 32 + i * 16 + kg * 4 + r;
        int row = m0 + row_l;
        float lr = acc[i][j][r] + bb;
        lr = fminf(5.0f, fmaxf(-5.0f, lr));
        float R = expf(lr);
        float K = Pi / fmaxf(Pi + R, 1e-8f);
        size_t o = (size_t)row * C_ + col;
        __builtin_nontemporal_store(Pi, &out1[o]);
        out2[o] = K;
        __builtin_nontemporal_store(R, &out3[o]);
        float nu = wrap_neg(theta[o]);
        sA[row_l * 132 + col_l] = 1.f - K;
        sU[row_l * 132 + col_l] = K * nu;
      }
    }
  __syncthreads();

  // segment composition: 4 segs of 16 rows per channel
  {
    int c_l = tid & 127, seg = tid >> 7;
    float A = 1.f, U = 0.f;
#pragma unroll
    for (int rr = seg * 16; rr < seg * 16 + 16; ++rr) {
      float a = sA[rr * 132 + c_l], u = sU[rr * 132 + c_l];
      U = a * U + u; A *= a;
    }
    sGA[seg * 132 + c_l] = A; sGU[seg * 132 + c_l] = U;
  }
  __syncthreads();

  // combine pairs -> per-32-row chunk composites, write to ws
  if (tid < 256) {
    int c_l = tid & 127, h = tid >> 7;
    float A0 = sGA[(2 * h) * 132 + c_l], U0 = sGU[(2 * h) * 132 + c_l];
    float A1 = sGA[(2 * h + 1) * 132 + c_l], U1 = sGU[(2 * h + 1) * 132 + c_l];
    float A = A1 * A0, U = A1 * U0 + U1;
    int b  = m0 >> 12;
    int ch = ((m0 & 4095) >> 5) + h;      // chunk-of-32 index
    size_t o = ((size_t)(b * NC_ + ch)) * C_ + n0 + c_l;
    Ab[o] = A; Ub[o] = U;
  }
}

// ---- scan2: block-level prefix over 128 chunks for 16 channels
__global__ __launch_bounds__(256) void k_scan2(const float* __restrict__ Ab,
                                               const float* __restrict__ Ub,
                                               float* __restrict__ D0) {
  __shared__ float cA[16][17], cU[16][17], carry[16][17];
  const int tid = threadIdx.x;
  const int b   = blockIdx.x >> 5;
  const int c0  = (blockIdx.x & 31) * 16;
  const int c_l = tid & 15, s = tid >> 4;   // 16 segs x 8 chunks
  const int c   = c0 + c_l;
  float A = 1.f, U = 0.f;
#pragma unroll
  for (int k = 0; k < 8; ++k) {
    size_t o = ((size_t)(b * NC_ + s * 8 + k)) * C_ + c;
    float a = Ab[o], u = Ub[o];
    U = a * U + u; A *= a;
  }
  cA[s][c_l] = A; cU[s][c_l] = U;
  __syncthreads();
  if (tid < 16) {
    float P = 0.f;
#pragma unroll
    for (int ss = 0; ss < 16; ++ss) {
      carry[ss][tid] = P;
      P = cA[ss][tid] * P + cU[ss][tid];
    }
  }
  __syncthreads();
  float d = carry[s][c_l];
#pragma unroll
  for (int k = 0; k < 8; ++k) {
    size_t o = ((size_t)(b * NC_ + s * 8 + k)) * C_ + c;
    D0[o] = d;
    d = Ab[o] * d + Ub[o];
  }
}

// ---- scan3: apply carry, out0 = theta + d
__global__ __launch_bounds__(256) void k_scan3(const float* __restrict__ Kv,
                                               const float* __restrict__ theta,
                                               const float* __restrict__ D0,
                                               float* __restrict__ out0) {
  const int b  = blockIdx.x / NC_;
  const int ch = blockIdx.x % NC_;
  const int c  = blockIdx.y * 256 + threadIdx.x;
  size_t base = ((size_t)b * L_ + (size_t)ch * CT_) * C_ + c;
  float d = D0[((size_t)(b * NC_ + ch)) * C_ + c];
#pragma unroll 4
  for (int j = 0; j < CT_; ++j) {
    size_t idx = base + (size_t)j * C_;
    float k  = Kv[idx];
    float th = theta[idx];
    float nu = wrap_neg(th);
    d = (1.f - k) * d + k * nu;
    __builtin_nontemporal_store(th + d, &out0[idx]);
  }
}

extern "C" void kernel_launch(void* const* d_in, const int* in_sizes, int n_in,
                              void* d_out, int out_size, void* d_ws, size_t ws_size,
                              hipStream_t stream) {
  const float* theta = (const float*)d_in[0];
  const float* X     = (const float*)d_in[1];
  const float* logPi = (const float*)d_in[2];
  const float* W1    = (const float*)d_in[3];
  const float* b1    = (const float*)d_in[4];
  const float* W2    = (const float*)d_in[5];
  const float* b2    = (const float*)d_in[6];

  float* out = (float*)d_out;
  const size_t S = (size_t)M_ * C_;
  float* out0 = out;
  float* out1 = out + S;
  float* out2 = out + 2 * S;
  float* out3 = out + 3 * S;

  unsigned short* Hb  = (unsigned short*)d_ws;
  unsigned short* W1T = Hb + (size_t)M_ * HID_;
  unsigned short* W2T = W1T + (size_t)DM_ * HID_;
  float* Ab = (float*)(W2T + (size_t)HID_ * C_);
  float* Ub = Ab + (size_t)B_ * NC_ * C_;
  float* D0 = Ub + (size_t)B_ * NC_ * C_;

  hipLaunchKernelGGL(k_prep, dim3(768), dim3(256), 0, stream, W1, W2, W1T, W2T);
  hipLaunchKernelGGL(k_gemm1, dim3(M_ / 64), dim3(512), 0, stream, X, W1T, b1, Hb);
  hipLaunchKernelGGL(k_gemm2, dim3(M_ / 64, C_ / 128), dim3(512), 0, stream,
                     Hb, W2T, b2, logPi, theta, out1, out2, out3, Ab, Ub);
  hipLaunchKernelGGL(k_scan2, dim3(B_ * 32), dim3(256), 0, stream, Ab, Ub, D0);
  hipLaunchKernelGGL(k_scan3, dim3(B_ * NC_, 2), dim3(256), 0, stream, out2, theta, D0, out0);
}

// Round 5
// 81.914 us; speedup vs baseline: 2.7399x; 1.0451x over previous
//
#include <hip/hip_runtime.h>
#include <math.h>

#define B_   4
#define L_   4096
#define C_   512
#define DM_  1024
#define HID_ 128
#define M_   (B_*L_)    // 16384
#define NC_  128        // chunks of 32 rows for scan2/scan3
#define CT_  32

typedef __attribute__((ext_vector_type(8))) short short8;
typedef __attribute__((ext_vector_type(4))) float f32x4;

__device__ __forceinline__ unsigned short f2bf(float f) {
  unsigned u = __float_as_uint(f);
  u += 0x7fffu + ((u >> 16) & 1u);
  return (unsigned short)(u >> 16);
}

// wrap(-theta) into (-pi, pi] == atan2(sin(-t), cos(-t))
__device__ __forceinline__ float wrap_neg(float th) {
  return 6.283185307179586f * rintf(th * 0.15915494309189535f) - th;
}

// ---- prep: transpose+cast weights to bf16 [n][k]
__global__ __launch_bounds__(256) void k_prep(const float* __restrict__ W1,
                                              const float* __restrict__ W2,
                                              unsigned short* __restrict__ W1T,
                                              unsigned short* __restrict__ W2T) {
  int idx = blockIdx.x * 256 + threadIdx.x;
  if (idx < DM_ * HID_) {
    int n = idx >> 10, k = idx & 1023;
    W1T[idx] = f2bf(W1[(size_t)k * HID_ + n]);
  }
  int i2 = idx - DM_ * HID_;
  if (i2 >= 0 && i2 < HID_ * C_) {
    int n = i2 >> 7, k = i2 & 127;
    W2T[i2] = f2bf(W2[(size_t)k * C_ + n]);
  }
}

// ---- mega: H=gelu(X@W1+b1) in LDS; logR=clip(H@W2+b2); Pi/K/R writes; per-32-row
//      affine chunk composites via register Horner + shfl butterfly.
// LDS map: [0,32768) staging (phase1: A 8K @0, B 16K @8192; phase2: B-tile 32K @0)
//          [32768,49152) H tile 64x128 bf16, swizzle-4
__global__ __launch_bounds__(512) void k_mega(const float* __restrict__ X,
                                              const unsigned short* __restrict__ W1T,
                                              const float* __restrict__ b1,
                                              const unsigned short* __restrict__ W2T,
                                              const float* __restrict__ b2,
                                              const float* __restrict__ logPi,
                                              const float* __restrict__ theta,
                                              float* __restrict__ out1,
                                              float* __restrict__ out2,
                                              float* __restrict__ out3,
                                              float* __restrict__ Ab,
                                              float* __restrict__ Ub) {
  __shared__ char lds[49152];
  const int tid  = threadIdx.x;
  const int m0   = blockIdx.x * 64;
  const int lane = tid & 63;
  const int wave = tid >> 6;
  const int wr   = wave >> 2;      // 0..1 : 32-row half
  const int wc   = wave & 3;       // 0..3 : 32-col group
  const int fr   = lane & 15;
  const int kg   = lane >> 4;      // 0..3

  // ---------------- phase 1: H = gelu(X @ W1 + b1) ----------------
  f32x4 acc[2][2];
#pragma unroll
  for (int i = 0; i < 2; ++i)
#pragma unroll
    for (int j = 0; j < 2; ++j) acc[i][j] = (f32x4){0.f, 0.f, 0.f, 0.f};

  for (int k0 = 0; k0 < DM_; k0 += 64) {
    {
      int row = tid >> 3, k8 = tid & 7;
      const f32x4* src = (const f32x4*)(X + (size_t)(m0 + row) * DM_ + k0 + k8 * 8);
      f32x4 v0 = __builtin_nontemporal_load(src);
      f32x4 v1 = __builtin_nontemporal_load(src + 1);
      uint4 pk;
      pk.x = f2bf(v0[0]) | ((unsigned)f2bf(v0[1]) << 16);
      pk.y = f2bf(v0[2]) | ((unsigned)f2bf(v0[3]) << 16);
      pk.z = f2bf(v1[0]) | ((unsigned)f2bf(v1[1]) << 16);
      pk.w = f2bf(v1[2]) | ((unsigned)f2bf(v1[3]) << 16);
      *(uint4*)(lds + row * 128 + ((k8 ^ (row & 7)) << 4)) = pk;
    }
#pragma unroll
    for (int t = 0; t < 2; ++t) {
      int c = tid + t * 512;
      int n = c >> 3, k8 = c & 7;
      uint4 v = *(const uint4*)(W1T + (size_t)n * DM_ + k0 + k8 * 8);
      *(uint4*)(lds + 8192 + n * 128 + ((k8 ^ (n & 7)) << 4)) = v;
    }
    __syncthreads();
#pragma unroll
    for (int ks = 0; ks < 2; ++ks) {
      short8 a[2], b[2];
#pragma unroll
      for (int i = 0; i < 2; ++i) {
        int row = wr * 32 + i * 16 + fr;
        a[i] = *(const short8*)(lds + row * 128 + (((ks * 4 + kg) ^ (row & 7)) << 4));
      }
#pragma unroll
      for (int j = 0; j < 2; ++j) {
        int col = wc * 32 + j * 16 + fr;
        b[j] = *(const short8*)(lds + 8192 + col * 128 + (((ks * 4 + kg) ^ (col & 7)) << 4));
      }
#pragma unroll
      for (int i = 0; i < 2; ++i)
#pragma unroll
        for (int j = 0; j < 2; ++j)
          acc[i][j] = __builtin_amdgcn_mfma_f32_16x16x32_bf16(a[i], b[j], acc[i][j], 0, 0, 0);
    }
    __syncthreads();
  }
  // H epilogue -> LDS region1 (bf16, swizzle-4 A-layout for phase 2)
#pragma unroll
  for (int i = 0; i < 2; ++i)
#pragma unroll
    for (int j = 0; j < 2; ++j) {
      int col = wc * 32 + j * 16 + fr;     // col == k-dim of phase 2
      float bb = b1[col];
#pragma unroll
      for (int r = 0; r < 4; ++r) {
        int row = wr * 32 + i * 16 + kg * 4 + r;
        float x = acc[i][j][r] + bb;
        float g = 0.5f * x * (1.0f + erff(x * 0.70710678f));
        *(unsigned short*)(lds + 32768 + row * 256 +
                           (((col >> 3) ^ (row & 15)) << 4) + ((col & 7) << 1)) = f2bf(g);
      }
    }

  // ---------------- phase 2: logR = clip(H @ W2 + b2) + outputs + scan composites ----
  const int bidx = m0 >> 12;
  const int ch   = ((m0 & 4095) >> 5) + wr;          // this wave's 32-row chunk
  const size_t chbase = ((size_t)(bidx * NC_ + ch)) * C_;

  for (int nc = 0; nc < 4; ++nc) {
    const int n0 = nc * 128;
    {   // stage B tile: 128 n x 128 k bf16, swizzle-4
      int n = tid >> 2;
      int k8b = (tid & 3) << 2;
      const unsigned short* src = W2T + (size_t)(n0 + n) * HID_ + k8b * 8;
#pragma unroll
      for (int q = 0; q < 4; ++q) {
        uint4 v = *(const uint4*)(src + q * 8);
        int k8 = k8b + q;
        *(uint4*)(lds + n * 256 + ((k8 ^ (n & 15)) << 4)) = v;
      }
    }
    __syncthreads();

    f32x4 a2[2][2];
#pragma unroll
    for (int i = 0; i < 2; ++i)
#pragma unroll
      for (int j = 0; j < 2; ++j) a2[i][j] = (f32x4){0.f, 0.f, 0.f, 0.f};
#pragma unroll
    for (int ks = 0; ks < 4; ++ks) {
      short8 af[2], bf2[2];
#pragma unroll
      for (int i = 0; i < 2; ++i) {
        int row = wr * 32 + i * 16 + fr;
        af[i] = *(const short8*)(lds + 32768 + row * 256 + (((ks * 4 + kg) ^ (row & 15)) << 4));
      }
#pragma unroll
      for (int j = 0; j < 2; ++j) {
        int col = wc * 32 + j * 16 + fr;
        bf2[j] = *(const short8*)(lds + col * 256 + (((ks * 4 + kg) ^ (col & 15)) << 4));
      }
#pragma unroll
      for (int i = 0; i < 2; ++i)
#pragma unroll
        for (int j = 0; j < 2; ++j)
          a2[i][j] = __builtin_amdgcn_mfma_f32_16x16x32_bf16(af[i], bf2[j], a2[i][j], 0, 0, 0);
    }

    // epilogue + in-register chunk composition
#pragma unroll
    for (int j = 0; j < 2; ++j) {
      int col = n0 + wc * 32 + j * 16 + fr;
      float Pi = expf(logPi[col]);
      float bb = b2[col];
      float A16[2], U16[2];
#pragma unroll
      for (int i = 0; i < 2; ++i) {
        float A = 1.f, U = 0.f;
#pragma unroll
        for (int r = 0; r < 4; ++r) {
          int row = m0 + wr * 32 + i * 16 + kg * 4 + r;
          float lr = a2[i][j][r] + bb;
          lr = fminf(5.0f, fmaxf(-5.0f, lr));
          float R = expf(lr);
          float K = Pi / fmaxf(Pi + R, 1e-8f);
          size_t o = (size_t)row * C_ + col;
          __builtin_nontemporal_store(Pi, &out1[o]);
          out2[o] = K;
          __builtin_nontemporal_store(R, &out3[o]);
          float nu = wrap_neg(theta[o]);
          float a = 1.f - K;
          U = a * U + K * nu;
          A = a * A;
        }
        // ordered combine across kg lanes (butterfly): kg 0,1,2,3 = row order
        float oA = __shfl_xor(A, 16), oU = __shfl_xor(U, 16);
        if ((kg & 1) == 0) { U = oA * U + oU; A = oA * A; }
        else               { U = A * oU + U;  A = A * oA; }
        oA = __shfl_xor(A, 32); oU = __shfl_xor(U, 32);
        if ((kg & 2) == 0) { U = oA * U + oU; A = oA * A; }
        else               { U = A * oU + U;  A = A * oA; }
        A16[i] = A; U16[i] = U;
      }
      float A32 = A16[1] * A16[0];
      float U32 = A16[1] * U16[0] + U16[1];
      if (kg == j) { Ab[chbase + col] = A32; Ub[chbase + col] = U32; }
    }
    __syncthreads();
  }
}

// ---- scan2: block-level prefix over 128 chunks for 16 channels
__global__ __launch_bounds__(256) void k_scan2(const float* __restrict__ Ab,
                                               const float* __restrict__ Ub,
                                               float* __restrict__ D0) {
  __shared__ float cA[16][17], cU[16][17], carry[16][17];
  const int tid = threadIdx.x;
  const int b   = blockIdx.x >> 5;
  const int c0  = (blockIdx.x & 31) * 16;
  const int c_l = tid & 15, s = tid >> 4;   // 16 segs x 8 chunks
  const int c   = c0 + c_l;
  float A = 1.f, U = 0.f;
#pragma unroll
  for (int k = 0; k < 8; ++k) {
    size_t o = ((size_t)(b * NC_ + s * 8 + k)) * C_ + c;
    float a = Ab[o], u = Ub[o];
    U = a * U + u; A *= a;
  }
  cA[s][c_l] = A; cU[s][c_l] = U;
  __syncthreads();
  if (tid < 16) {
    float P = 0.f;
#pragma unroll
    for (int ss = 0; ss < 16; ++ss) {
      carry[ss][tid] = P;
      P = cA[ss][tid] * P + cU[ss][tid];
    }
  }
  __syncthreads();
  float d = carry[s][c_l];
#pragma unroll
  for (int k = 0; k < 8; ++k) {
    size_t o = ((size_t)(b * NC_ + s * 8 + k)) * C_ + c;
    D0[o] = d;
    d = Ab[o] * d + Ub[o];
  }
}

// ---- scan3: apply carry, out0 = theta + d
__global__ __launch_bounds__(256) void k_scan3(const float* __restrict__ Kv,
                                               const float* __restrict__ theta,
                                               const float* __restrict__ D0,
                                               float* __restrict__ out0) {
  const int b  = blockIdx.x / NC_;
  const int ch = blockIdx.x % NC_;
  const int c  = blockIdx.y * 256 + threadIdx.x;
  size_t base = ((size_t)b * L_ + (size_t)ch * CT_) * C_ + c;
  float d = D0[((size_t)(b * NC_ + ch)) * C_ + c];
#pragma unroll 4
  for (int j = 0; j < CT_; ++j) {
    size_t idx = base + (size_t)j * C_;
    float k  = Kv[idx];
    float th = theta[idx];
    float nu = wrap_neg(th);
    d = (1.f - k) * d + k * nu;
    __builtin_nontemporal_store(th + d, &out0[idx]);
  }
}

extern "C" void kernel_launch(void* const* d_in, const int* in_sizes, int n_in,
                              void* d_out, int out_size, void* d_ws, size_t ws_size,
                              hipStream_t stream) {
  const float* theta = (const float*)d_in[0];
  const float* X     = (const float*)d_in[1];
  const float* logPi = (const float*)d_in[2];
  const float* W1    = (const float*)d_in[3];
  const float* b1    = (const float*)d_in[4];
  const float* W2    = (const float*)d_in[5];
  const float* b2    = (const float*)d_in[6];

  float* out = (float*)d_out;
  const size_t S = (size_t)M_ * C_;
  float* out0 = out;
  float* out1 = out + S;
  float* out2 = out + 2 * S;
  float* out3 = out + 3 * S;

  unsigned short* W1T = (unsigned short*)d_ws;           // 131072 ush
  unsigned short* W2T = W1T + (size_t)DM_ * HID_;        // 65536 ush
  float* Ab = (float*)(W2T + (size_t)HID_ * C_);         // B*NC*C f32 each
  float* Ub = Ab + (size_t)B_ * NC_ * C_;
  float* D0 = Ub + (size_t)B_ * NC_ * C_;

  hipLaunchKernelGGL(k_prep, dim3(768), dim3(256), 0, stream, W1, W2, W1T, W2T);
  hipLaunchKernelGGL(k_mega, dim3(M_ / 64), dim3(512), 0, stream,
                     X, W1T, b1, W2T, b2, logPi, theta, out1, out2, out3, Ab, Ub);
  hipLaunchKernelGGL(k_scan2, dim3(B_ * 32), dim3(256), 0, stream, Ab, Ub, D0);
  hipLaunchKernelGGL(k_scan3, dim3(B_ * NC_, 2), dim3(256), 0, stream, out2, theta, D0, out0);
}